// Round 2
// baseline (1586.636 us; speedup 1.0000x reference)
//
#include <hip/hip_runtime.h>
#include <cmath>

typedef __attribute__((ext_vector_type(8))) _Float16 f16x8;
typedef __attribute__((ext_vector_type(8))) unsigned short u16x8;
typedef __attribute__((ext_vector_type(4))) float f32x4;

__device__ __forceinline__ unsigned short f2h(float f) {
  return __builtin_bit_cast(unsigned short, (_Float16)f);
}

__device__ __forceinline__ void async16(const void* gp, void* lp) {
  __builtin_amdgcn_global_load_lds(
      (const __attribute__((address_space(1))) void*)gp,
      (__attribute__((address_space(3))) void*)lp, 16, 0, 0);
}

// ---------------- weight transpose + cast: W (K x N) f32 -> WT (N x K) f16 ----
__global__ __launch_bounds__(256) void transpose_cast(
    const float* __restrict__ W, unsigned short* __restrict__ WT, int K, int N) {
  __shared__ float tile[32][33];
  const int tx = threadIdx.x & 31, ty = threadIdx.x >> 5;
  const int n0 = blockIdx.x * 32, k0 = blockIdx.y * 32;
#pragma unroll
  for (int r = 0; r < 4; ++r)
    tile[ty + 8 * r][tx] = W[(size_t)(k0 + ty + 8 * r) * N + n0 + tx];
  __syncthreads();
#pragma unroll
  for (int r = 0; r < 4; ++r)
    WT[(size_t)(n0 + ty + 8 * r) * K + k0 + tx] = f2h(tile[tx][ty + 8 * r]);
}

// ---------------- layernorm (C=1024) f32 -> f16 ------------------------------
__global__ __launch_bounds__(256) void layernorm_cast(
    const float* __restrict__ x, const float* __restrict__ g,
    const float* __restrict__ bt, unsigned short* __restrict__ out) {
  const int row = blockIdx.x, tid = threadIdx.x;
  const float4 v = ((const float4*)(x + (size_t)row * 1024))[tid];
  float s = v.x + v.y + v.z + v.w;
  float ss = v.x * v.x + v.y * v.y + v.z * v.z + v.w * v.w;
#pragma unroll
  for (int off = 32; off >= 1; off >>= 1) {
    s += __shfl_down(s, off);
    ss += __shfl_down(ss, off);
  }
  __shared__ float red[10];
  const int wave = tid >> 6, lane = tid & 63;
  if (lane == 0) { red[wave] = s; red[4 + wave] = ss; }
  __syncthreads();
  if (tid == 0) {
    float S = red[0] + red[1] + red[2] + red[3];
    float SS = red[4] + red[5] + red[6] + red[7];
    float mu = S * (1.f / 1024.f);
    float var = SS * (1.f / 1024.f) - mu * mu;
    red[8] = mu;
    red[9] = rsqrtf(var + 1e-5f);
  }
  __syncthreads();
  const float mu = red[8], rs = red[9];
  const float4 gv = ((const float4*)g)[tid];
  const float4 bv = ((const float4*)bt)[tid];
  ushort4 r;
  r.x = f2h((v.x - mu) * rs * gv.x + bv.x);
  r.y = f2h((v.y - mu) * rs * gv.y + bv.y);
  r.z = f2h((v.z - mu) * rs * gv.z + bv.z);
  r.w = f2h((v.w - mu) * rs * gv.w + bv.w);
  ((ushort4*)(out + (size_t)row * 1024))[tid] = r;
}

// ---------------- m97-style f16 GEMM: C = A (MxK) * BT^T (BT is NxK) ---------
// mode 0: outB = f16(acc)
// mode 1: outF = acc + bias[col] + resid[row][col]   (fp32 out)
// mode 2: outB = f16(gelu_exact(acc + bias[col]))
__global__ __launch_bounds__(256) void gemm_bt(
    const unsigned short* __restrict__ A, const unsigned short* __restrict__ BT,
    int M, int N, int K,
    const float* __restrict__ bias, const float* __restrict__ resid,
    float* __restrict__ outF, unsigned short* __restrict__ outB, int mode) {
  __shared__ unsigned short sA[128 * 32];
  __shared__ unsigned short sB[128 * 32];
  const int tid = threadIdx.x, wave = tid >> 6, lane = tid & 63;
  const int l16 = lane & 15, g16 = lane >> 4;
  const int wm = wave & 1, wn = wave >> 1;
  const int row0 = blockIdx.y * 128, col0 = blockIdx.x * 128;

  f32x4 acc[4][4] = {};

  for (int k0 = 0; k0 < K; k0 += 32) {
    __syncthreads();
#pragma unroll
    for (int t = 0; t < 2; ++t) {
      const int c = t * 256 + wave * 64 + lane;
      const int r = c >> 2, sgi = c & 3;
      async16(A + (size_t)(row0 + r) * K + k0 + sgi * 8,
              sA + (size_t)(t * 256 + wave * 64) * 8);
      async16(BT + (size_t)(col0 + r) * K + k0 + sgi * 8,
              sB + (size_t)(t * 256 + wave * 64) * 8);
    }
    __syncthreads();
    f16x8 af[4], bf[4];
#pragma unroll
    for (int i = 0; i < 4; ++i)
      af[i] = __builtin_bit_cast(f16x8,
          *(const u16x8*)&sA[(wm * 64 + i * 16 + l16) * 32 + g16 * 8]);
#pragma unroll
    for (int j = 0; j < 4; ++j)
      bf[j] = __builtin_bit_cast(f16x8,
          *(const u16x8*)&sB[(wn * 64 + j * 16 + l16) * 32 + g16 * 8]);
#pragma unroll
    for (int i = 0; i < 4; ++i)
#pragma unroll
      for (int j = 0; j < 4; ++j)
        acc[i][j] = __builtin_amdgcn_mfma_f32_16x16x32_f16(af[i], bf[j], acc[i][j], 0, 0, 0);
  }

#pragma unroll
  for (int i = 0; i < 4; ++i) {
#pragma unroll
    for (int j = 0; j < 4; ++j) {
      const int col = col0 + wn * 64 + j * 16 + l16;
#pragma unroll
      for (int r = 0; r < 4; ++r) {
        const int row = row0 + wm * 64 + i * 16 + g16 * 4 + r;
        const size_t idx = (size_t)row * N + col;
        const float val = acc[i][j][r];
        if (mode == 1) {
          outF[idx] = val + bias[col] + resid[idx];
        } else if (mode == 2) {
          const float t = val + bias[col];
          outB[idx] = f2h(0.5f * t * (1.0f + erff(t * 0.70710678118f)));
        } else {
          outB[idx] = f2h(val);
        }
      }
    }
  }
}

// ---------------- attention over head_dim (d x d scores, contraction over N) --
// q,k,v: (M x C) f16 in the row-major "Qmat[b*N+n][h*64+dd]" layout.
// S[dd][e] = sum_n Q[n][dd] K[n][e];  A = softmax(S*0.125, axis e)
// o_val(b,h,dd,n) = sum_e A[dd][e] V[n][e]
// scrambled output: o[b*4096 + dd*64 + h*4 + (n>>10)][n & 1023]
__global__ __launch_bounds__(256) void attention_kernel(
    const unsigned short* __restrict__ q, const unsigned short* __restrict__ k,
    const unsigned short* __restrict__ v, unsigned short* __restrict__ o) {
  constexpr int ST = 72;  // padded LDS stride (rows stay 16B-aligned)
  __shared__ unsigned short sQT[64 * ST];  // [dd][n]
  __shared__ unsigned short sKT[64 * ST];  // [e][n]
  __shared__ float sS[64 * 64];
  __shared__ unsigned short sAm[64 * ST];  // softmaxed A, [dd][e], f16

  const int bh = blockIdx.x, b = bh >> 4, h = bh & 15;
  const size_t base = (size_t)b * 4096 * 1024 + (size_t)h * 64;
  const int tid = threadIdx.x, wave = tid >> 6, lane = tid & 63;
  const int l16 = lane & 15, g16 = lane >> 4;
  const int wm = wave & 1, wn = wave >> 1;
  const int srow = tid >> 2, sseg = tid & 3;

  f32x4 acc[2][2] = {};

  // phase 1: S = Q^T K, n-tiles of 64
  for (int nt = 0; nt < 64; ++nt) {
    __syncthreads();
    const size_t roff = base + (size_t)(nt * 64 + srow) * 1024 + sseg * 16;
    const u16x8 q0 = *(const u16x8*)(q + roff);
    const u16x8 q1 = *(const u16x8*)(q + roff + 8);
    const u16x8 k0 = *(const u16x8*)(k + roff);
    const u16x8 k1 = *(const u16x8*)(k + roff + 8);
#pragma unroll
    for (int ii = 0; ii < 8; ++ii) {
      sQT[(sseg * 16 + ii) * ST + srow] = q0[ii];
      sQT[(sseg * 16 + 8 + ii) * ST + srow] = q1[ii];
      sKT[(sseg * 16 + ii) * ST + srow] = k0[ii];
      sKT[(sseg * 16 + 8 + ii) * ST + srow] = k1[ii];
    }
    __syncthreads();
#pragma unroll
    for (int kk = 0; kk < 2; ++kk) {
      f16x8 aq[2], bk[2];
#pragma unroll
      for (int i = 0; i < 2; ++i)
        aq[i] = __builtin_bit_cast(f16x8,
            *(const u16x8*)&sQT[(wm * 32 + i * 16 + l16) * ST + kk * 32 + g16 * 8]);
#pragma unroll
      for (int j = 0; j < 2; ++j)
        bk[j] = __builtin_bit_cast(f16x8,
            *(const u16x8*)&sKT[(wn * 32 + j * 16 + l16) * ST + kk * 32 + g16 * 8]);
#pragma unroll
      for (int i = 0; i < 2; ++i)
#pragma unroll
        for (int j = 0; j < 2; ++j)
          acc[i][j] = __builtin_amdgcn_mfma_f32_16x16x32_f16(aq[i], bk[j], acc[i][j], 0, 0, 0);
    }
  }
#pragma unroll
  for (int i = 0; i < 2; ++i)
#pragma unroll
    for (int j = 0; j < 2; ++j)
#pragma unroll
      for (int r = 0; r < 4; ++r)
        sS[(wm * 32 + i * 16 + g16 * 4 + r) * 64 + (wn * 32 + j * 16 + l16)] = acc[i][j][r];
  __syncthreads();

  // softmax over e, scale = d^-0.5 = 0.125
  if (tid < 64) {
    const int dd = tid;
    float mx = -1e30f;
    for (int e = 0; e < 64; ++e) mx = fmaxf(mx, sS[dd * 64 + e]);
    float sum = 0.f;
    for (int e = 0; e < 64; ++e) {
      const float t = __expf(0.125f * (sS[dd * 64 + e] - mx));
      sum += t;
      sS[dd * 64 + e] = t;
    }
    const float inv = 1.0f / sum;
    for (int e = 0; e < 64; ++e) sAm[dd * ST + e] = f2h(sS[dd * 64 + e] * inv);
  }
  __syncthreads();

  // phase 2: O_t[dd][n] = sum_e A[dd][e] * V[n][e]
  f16x8 am[2][2];
#pragma unroll
  for (int i = 0; i < 2; ++i)
#pragma unroll
    for (int kk = 0; kk < 2; ++kk)
      am[i][kk] = __builtin_bit_cast(f16x8,
          *(const u16x8*)&sAm[(wm * 32 + i * 16 + l16) * ST + kk * 32 + g16 * 8]);

  for (int nt = 0; nt < 64; ++nt) {
    f32x4 oc[2][2] = {};
#pragma unroll
    for (int kk = 0; kk < 2; ++kk) {
#pragma unroll
      for (int j = 0; j < 2; ++j) {
        const f16x8 vf = __builtin_bit_cast(f16x8,
            *(const u16x8*)(v + base +
                            (size_t)(nt * 64 + wn * 32 + j * 16 + l16) * 1024 +
                            kk * 32 + g16 * 8));
#pragma unroll
        for (int i = 0; i < 2; ++i)
          oc[i][j] = __builtin_amdgcn_mfma_f32_16x16x32_f16(am[i][kk], vf, oc[i][j], 0, 0, 0);
      }
    }
#pragma unroll
    for (int i = 0; i < 2; ++i)
#pragma unroll
      for (int j = 0; j < 2; ++j)
#pragma unroll
        for (int r = 0; r < 4; ++r) {
          const int dd = wm * 32 + i * 16 + g16 * 4 + r;
          const int nf = nt * 64 + wn * 32 + j * 16 + l16;
          const int row = b * 4096 + dd * 64 + h * 4 + (nf >> 10);
          o[(size_t)row * 1024 + (nf & 1023)] = f2h(oc[i][j][r]);
        }
  }
}

// -----------------------------------------------------------------------------
extern "C" void kernel_launch(void* const* d_in, const int* in_sizes, int n_in,
                              void* d_out, int out_size, void* d_ws, size_t ws_size,
                              hipStream_t stream) {
  (void)in_sizes; (void)n_in; (void)out_size; (void)ws_size;
  const float* x = (const float*)d_in[0];
  const float* ln1g = (const float*)d_in[1];
  const float* ln1b = (const float*)d_in[2];
  const float* ln2g = (const float*)d_in[3];
  const float* ln2b = (const float*)d_in[4];
  const float* wq = (const float*)d_in[5];
  const float* wk = (const float*)d_in[6];
  const float* wv = (const float*)d_in[7];
  const float* projw = (const float*)d_in[8];
  const float* projb = (const float*)d_in[9];
  const float* fc1w = (const float*)d_in[10];
  const float* fc1b = (const float*)d_in[11];
  const float* fc2w = (const float*)d_in[12];
  const float* fc2b = (const float*)d_in[13];
  float* out = (float*)d_out;

  const int M = 8 * 4096, C = 1024, HF = 2048;

  unsigned short* p = (unsigned short*)d_ws;
  unsigned short* wqT = p; p += (size_t)C * C;
  unsigned short* wkT = p; p += (size_t)C * C;
  unsigned short* wvT = p; p += (size_t)C * C;
  unsigned short* prT = p; p += (size_t)C * C;
  unsigned short* f1T = p; p += (size_t)HF * C;
  unsigned short* f2T = p; p += (size_t)C * HF;
  unsigned short* hb = p;  p += (size_t)M * C;
  unsigned short* qb = p;  p += (size_t)M * C;
  unsigned short* kb = p;  p += (size_t)M * C;
  unsigned short* vb = p;  p += (size_t)M * C;
  unsigned short* ob = hb;   // reuse: h dead after qkv
  unsigned short* h2 = qb;   // reuse: q dead after attention
  unsigned short* h3 = kb;   // reuse: k+v (contiguous 128MB) dead after attention

  transpose_cast<<<dim3(C / 32, C / 32), 256, 0, stream>>>(wq, wqT, C, C);
  transpose_cast<<<dim3(C / 32, C / 32), 256, 0, stream>>>(wk, wkT, C, C);
  transpose_cast<<<dim3(C / 32, C / 32), 256, 0, stream>>>(wv, wvT, C, C);
  transpose_cast<<<dim3(C / 32, C / 32), 256, 0, stream>>>(projw, prT, C, C);
  transpose_cast<<<dim3(HF / 32, C / 32), 256, 0, stream>>>(fc1w, f1T, C, HF);
  transpose_cast<<<dim3(C / 32, HF / 32), 256, 0, stream>>>(fc2w, f2T, HF, C);

  layernorm_cast<<<M, 256, 0, stream>>>(x, ln1g, ln1b, hb);

  const dim3 g1(C / 128, M / 128);
  gemm_bt<<<g1, 256, 0, stream>>>(hb, wqT, M, C, C, nullptr, nullptr, nullptr, qb, 0);
  gemm_bt<<<g1, 256, 0, stream>>>(hb, wkT, M, C, C, nullptr, nullptr, nullptr, kb, 0);
  gemm_bt<<<g1, 256, 0, stream>>>(hb, wvT, M, C, C, nullptr, nullptr, nullptr, vb, 0);

  attention_kernel<<<128, 256, 0, stream>>>(qb, kb, vb, ob);

  gemm_bt<<<g1, 256, 0, stream>>>(ob, prT, M, C, C, projb, x, out, nullptr, 1);

  layernorm_cast<<<M, 256, 0, stream>>>(out, ln2g, ln2b, h2);

  gemm_bt<<<dim3(HF / 128, M / 128), 256, 0, stream>>>(h2, f1T, M, HF, C, fc1b, nullptr, nullptr, h3, 2);
  gemm_bt<<<g1, 256, 0, stream>>>(h3, f2T, M, C, HF, fc2b, out, out, nullptr, 1);
}

// Round 3
// 1506.445 us; speedup vs baseline: 1.0532x; 1.0532x over previous
//
#include <hip/hip_runtime.h>
#include <cmath>

typedef __attribute__((ext_vector_type(8))) _Float16 f16x8;
typedef __attribute__((ext_vector_type(8))) unsigned short u16x8;
typedef __attribute__((ext_vector_type(4))) float f32x4;

__device__ __forceinline__ unsigned short f2h(float f) {
  return __builtin_bit_cast(unsigned short, (_Float16)f);
}

__device__ __forceinline__ void async16(const void* gp, void* lp) {
  __builtin_amdgcn_global_load_lds(
      (const __attribute__((address_space(1))) void*)gp,
      (__attribute__((address_space(3))) void*)lp, 16, 0, 0);
}

// ---------------- weight transpose + cast: W (K x N) f32 -> WT (N x K) f16 ----
__global__ __launch_bounds__(256) void transpose_cast(
    const float* __restrict__ W, unsigned short* __restrict__ WT, int K, int N) {
  __shared__ float tile[32][33];
  const int tx = threadIdx.x & 31, ty = threadIdx.x >> 5;
  const int n0 = blockIdx.x * 32, k0 = blockIdx.y * 32;
#pragma unroll
  for (int r = 0; r < 4; ++r)
    tile[ty + 8 * r][tx] = W[(size_t)(k0 + ty + 8 * r) * N + n0 + tx];
  __syncthreads();
#pragma unroll
  for (int r = 0; r < 4; ++r)
    WT[(size_t)(n0 + ty + 8 * r) * K + k0 + tx] = f2h(tile[tx][ty + 8 * r]);
}

// ---------------- layernorm (C=1024) f32 -> f16 ------------------------------
__global__ __launch_bounds__(256) void layernorm_cast(
    const float* __restrict__ x, const float* __restrict__ g,
    const float* __restrict__ bt, unsigned short* __restrict__ out) {
  const int row = blockIdx.x, tid = threadIdx.x;
  const float4 v = ((const float4*)(x + (size_t)row * 1024))[tid];
  float s = v.x + v.y + v.z + v.w;
  float ss = v.x * v.x + v.y * v.y + v.z * v.z + v.w * v.w;
#pragma unroll
  for (int off = 32; off >= 1; off >>= 1) {
    s += __shfl_down(s, off);
    ss += __shfl_down(ss, off);
  }
  __shared__ float red[10];
  const int wave = tid >> 6, lane = tid & 63;
  if (lane == 0) { red[wave] = s; red[4 + wave] = ss; }
  __syncthreads();
  if (tid == 0) {
    float S = red[0] + red[1] + red[2] + red[3];
    float SS = red[4] + red[5] + red[6] + red[7];
    float mu = S * (1.f / 1024.f);
    float var = SS * (1.f / 1024.f) - mu * mu;
    red[8] = mu;
    red[9] = rsqrtf(var + 1e-5f);
  }
  __syncthreads();
  const float mu = red[8], rs = red[9];
  const float4 gv = ((const float4*)g)[tid];
  const float4 bv = ((const float4*)bt)[tid];
  ushort4 r;
  r.x = f2h((v.x - mu) * rs * gv.x + bv.x);
  r.y = f2h((v.y - mu) * rs * gv.y + bv.y);
  r.z = f2h((v.z - mu) * rs * gv.z + bv.z);
  r.w = f2h((v.w - mu) * rs * gv.w + bv.w);
  ((ushort4*)(out + (size_t)row * 1024))[tid] = r;
}

// ---------------- f16 GEMM: C = A (MxK) * BT^T (BT is NxK) -------------------
// XOR-swizzled LDS (bank-conflict-free) + XCD-aware block remap.
// mode 0: outB = f16(acc)
// mode 1: outF = acc + bias[col] + resid[row][col]   (fp32 out)
// mode 2: outB = f16(gelu_exact(acc + bias[col]))
__global__ __launch_bounds__(256) void gemm_bt(
    const unsigned short* __restrict__ A, const unsigned short* __restrict__ BT,
    int M, int N, int K,
    const float* __restrict__ bias, const float* __restrict__ resid,
    float* __restrict__ outF, unsigned short* __restrict__ outB, int mode) {
  __shared__ unsigned short sA[128 * 32];
  __shared__ unsigned short sB[128 * 32];
  const int tid = threadIdx.x, wave = tid >> 6, lane = tid & 63;
  const int l16 = lane & 15, g16 = lane >> 4;
  const int wm = wave & 1, wn = wave >> 1;

  // XCD-aware remap: the gridDim.x column-blocks sharing one A row-tile land
  // on the SAME XCD (linear ids differing by 8) and are temporally adjacent.
  const int lin = blockIdx.y * gridDim.x + blockIdx.x;
  const int t_ = lin >> 3;
  const int bx = t_ % gridDim.x;
  const int by = (lin & 7) + 8 * (t_ / gridDim.x);
  const int row0 = by * 128, col0 = bx * 128;

  f32x4 acc[4][4] = {};

  for (int k0 = 0; k0 < K; k0 += 32) {
    __syncthreads();
#pragma unroll
    for (int t = 0; t < 2; ++t) {
      const int c = t * 256 + tid;
      const int r = c >> 2;
      const int s = (c & 3) ^ ((r >> 1) & 3);  // XOR segment swizzle
      async16(A + (size_t)(row0 + r) * K + k0 + s * 8,
              sA + (size_t)(t * 256 + wave * 64) * 8);
      async16(BT + (size_t)(col0 + r) * K + k0 + s * 8,
              sB + (size_t)(t * 256 + wave * 64) * 8);
    }
    __syncthreads();
    f16x8 af[4], bf[4];
#pragma unroll
    for (int i = 0; i < 4; ++i) {
      const int ra = wm * 64 + i * 16 + l16;
      af[i] = __builtin_bit_cast(f16x8,
          *(const u16x8*)&sA[ra * 32 + (g16 ^ ((ra >> 1) & 3)) * 8]);
    }
#pragma unroll
    for (int j = 0; j < 4; ++j) {
      const int rb = wn * 64 + j * 16 + l16;
      bf[j] = __builtin_bit_cast(f16x8,
          *(const u16x8*)&sB[rb * 32 + (g16 ^ ((rb >> 1) & 3)) * 8]);
    }
#pragma unroll
    for (int i = 0; i < 4; ++i)
#pragma unroll
      for (int j = 0; j < 4; ++j)
        acc[i][j] = __builtin_amdgcn_mfma_f32_16x16x32_f16(af[i], bf[j], acc[i][j], 0, 0, 0);
  }

#pragma unroll
  for (int i = 0; i < 4; ++i) {
#pragma unroll
    for (int j = 0; j < 4; ++j) {
      const int col = col0 + wn * 64 + j * 16 + l16;
      const float bcol = (mode != 0) ? bias[col] : 0.f;
#pragma unroll
      for (int r = 0; r < 4; ++r) {
        const int row = row0 + wm * 64 + i * 16 + g16 * 4 + r;
        const size_t idx = (size_t)row * N + col;
        const float val = acc[i][j][r];
        if (mode == 1) {
          outF[idx] = val + bcol + resid[idx];
        } else if (mode == 2) {
          const float t = val + bcol;
          outB[idx] = f2h(0.5f * t * (1.0f + erff(t * 0.70710678118f)));
        } else {
          outB[idx] = f2h(val);
        }
      }
    }
  }
}

// ---------------- attention over head_dim (d x d scores, contraction over N) --
// qkv: (M x 3072) f16; q at cols 0..1023, k at 1024..2047, v at 2048..3071.
// S[dd][e] = sum_n Q[n][dd] K[n][e];  A = softmax(S*0.125, axis e)
// o_val(b,h,dd,n) = sum_e A[dd][e] V[n][e]
// scrambled output: o[b*4096 + dd*64 + h*4 + (n>>10)][n & 1023]
__global__ __launch_bounds__(256) void attention_kernel(
    const unsigned short* __restrict__ qkv, unsigned short* __restrict__ o) {
  constexpr int ST = 72;  // padded LDS stride (rows stay 16B-aligned)
  __shared__ unsigned short sQT[64 * ST];  // [dd][n]
  __shared__ unsigned short sKT[64 * ST];  // [e][n]
  __shared__ float sS[64 * 64];
  __shared__ unsigned short sAm[64 * ST];  // softmaxed A, [dd][e], f16

  const int bh = blockIdx.x, b = bh >> 4, h = bh & 15;
  const size_t base = (size_t)b * 4096 * 3072 + (size_t)h * 64;
  const int tid = threadIdx.x, wave = tid >> 6, lane = tid & 63;
  const int l16 = lane & 15, g16 = lane >> 4;
  const int wm = wave & 1, wn = wave >> 1;
  const int srow = tid >> 2, sseg = tid & 3;

  f32x4 acc[2][2] = {};

  // phase 1: S = Q^T K, n-tiles of 64
  for (int nt = 0; nt < 64; ++nt) {
    __syncthreads();
    const size_t roff = base + (size_t)(nt * 64 + srow) * 3072 + sseg * 16;
    const u16x8 q0 = *(const u16x8*)(qkv + roff);
    const u16x8 q1 = *(const u16x8*)(qkv + roff + 8);
    const u16x8 k0 = *(const u16x8*)(qkv + roff + 1024);
    const u16x8 k1 = *(const u16x8*)(qkv + roff + 1032);
#pragma unroll
    for (int ii = 0; ii < 8; ++ii) {
      sQT[(sseg * 16 + ii) * ST + srow] = q0[ii];
      sQT[(sseg * 16 + 8 + ii) * ST + srow] = q1[ii];
      sKT[(sseg * 16 + ii) * ST + srow] = k0[ii];
      sKT[(sseg * 16 + 8 + ii) * ST + srow] = k1[ii];
    }
    __syncthreads();
#pragma unroll
    for (int kk = 0; kk < 2; ++kk) {
      f16x8 aq[2], bk[2];
#pragma unroll
      for (int i = 0; i < 2; ++i)
        aq[i] = __builtin_bit_cast(f16x8,
            *(const u16x8*)&sQT[(wm * 32 + i * 16 + l16) * ST + kk * 32 + g16 * 8]);
#pragma unroll
      for (int j = 0; j < 2; ++j)
        bk[j] = __builtin_bit_cast(f16x8,
            *(const u16x8*)&sKT[(wn * 32 + j * 16 + l16) * ST + kk * 32 + g16 * 8]);
#pragma unroll
      for (int i = 0; i < 2; ++i)
#pragma unroll
        for (int j = 0; j < 2; ++j)
          acc[i][j] = __builtin_amdgcn_mfma_f32_16x16x32_f16(aq[i], bk[j], acc[i][j], 0, 0, 0);
    }
  }
#pragma unroll
  for (int i = 0; i < 2; ++i)
#pragma unroll
    for (int j = 0; j < 2; ++j)
#pragma unroll
      for (int r = 0; r < 4; ++r)
        sS[(wm * 32 + i * 16 + g16 * 4 + r) * 64 + (wn * 32 + j * 16 + l16)] = acc[i][j][r];
  __syncthreads();

  // softmax over e, scale = d^-0.5 = 0.125
  if (tid < 64) {
    const int dd = tid;
    float mx = -1e30f;
    for (int e = 0; e < 64; ++e) mx = fmaxf(mx, sS[dd * 64 + e]);
    float sum = 0.f;
    for (int e = 0; e < 64; ++e) {
      const float t = __expf(0.125f * (sS[dd * 64 + e] - mx));
      sum += t;
      sS[dd * 64 + e] = t;
    }
    const float inv = 1.0f / sum;
    for (int e = 0; e < 64; ++e) sAm[dd * ST + e] = f2h(sS[dd * 64 + e] * inv);
  }
  __syncthreads();

  // phase 2: O_t[dd][n] = sum_e A[dd][e] * V[n][e]
  f16x8 am[2][2];
#pragma unroll
  for (int i = 0; i < 2; ++i)
#pragma unroll
    for (int kk = 0; kk < 2; ++kk)
      am[i][kk] = __builtin_bit_cast(f16x8,
          *(const u16x8*)&sAm[(wm * 32 + i * 16 + l16) * ST + kk * 32 + g16 * 8]);

  for (int nt = 0; nt < 64; ++nt) {
    f32x4 oc[2][2] = {};
#pragma unroll
    for (int kk = 0; kk < 2; ++kk) {
#pragma unroll
      for (int j = 0; j < 2; ++j) {
        const f16x8 vf = __builtin_bit_cast(f16x8,
            *(const u16x8*)(qkv + base + 2048 +
                            (size_t)(nt * 64 + wn * 32 + j * 16 + l16) * 3072 +
                            kk * 32 + g16 * 8));
#pragma unroll
        for (int i = 0; i < 2; ++i)
          oc[i][j] = __builtin_amdgcn_mfma_f32_16x16x32_f16(am[i][kk], vf, oc[i][j], 0, 0, 0);
      }
    }
#pragma unroll
    for (int i = 0; i < 2; ++i)
#pragma unroll
      for (int j = 0; j < 2; ++j)
#pragma unroll
        for (int r = 0; r < 4; ++r) {
          const int dd = wm * 32 + i * 16 + g16 * 4 + r;
          const int nf = nt * 64 + wn * 32 + j * 16 + l16;
          const int row = b * 4096 + dd * 64 + h * 4 + (nf >> 10);
          o[(size_t)row * 1024 + (nf & 1023)] = f2h(oc[i][j][r]);
        }
  }
}

// -----------------------------------------------------------------------------
extern "C" void kernel_launch(void* const* d_in, const int* in_sizes, int n_in,
                              void* d_out, int out_size, void* d_ws, size_t ws_size,
                              hipStream_t stream) {
  (void)in_sizes; (void)n_in; (void)out_size; (void)ws_size;
  const float* x = (const float*)d_in[0];
  const float* ln1g = (const float*)d_in[1];
  const float* ln1b = (const float*)d_in[2];
  const float* ln2g = (const float*)d_in[3];
  const float* ln2b = (const float*)d_in[4];
  const float* wq = (const float*)d_in[5];
  const float* wk = (const float*)d_in[6];
  const float* wv = (const float*)d_in[7];
  const float* projw = (const float*)d_in[8];
  const float* projb = (const float*)d_in[9];
  const float* fc1w = (const float*)d_in[10];
  const float* fc1b = (const float*)d_in[11];
  const float* fc2w = (const float*)d_in[12];
  const float* fc2b = (const float*)d_in[13];
  float* out = (float*)d_out;

  const int M = 8 * 4096, C = 1024, HF = 2048;

  unsigned short* p = (unsigned short*)d_ws;
  unsigned short* wqkvT = p; p += (size_t)3 * C * C;  // [3072 x 1024]
  unsigned short* prT = p; p += (size_t)C * C;
  unsigned short* f1T = p; p += (size_t)HF * C;
  unsigned short* f2T = p; p += (size_t)C * HF;
  unsigned short* hb = p;  p += (size_t)M * C;
  unsigned short* qkvb = p; p += (size_t)M * 3 * C;
  unsigned short* ob = hb;           // reuse: h dead after qkv GEMM
  unsigned short* h2 = qkvb;         // reuse: qkv dead after attention (M x C)
  unsigned short* h3 = qkvb + (size_t)M * C;  // (M x HF)

  transpose_cast<<<dim3(C / 32, C / 32), 256, 0, stream>>>(wq, wqkvT, C, C);
  transpose_cast<<<dim3(C / 32, C / 32), 256, 0, stream>>>(wk, wqkvT + (size_t)C * C, C, C);
  transpose_cast<<<dim3(C / 32, C / 32), 256, 0, stream>>>(wv, wqkvT + (size_t)2 * C * C, C, C);
  transpose_cast<<<dim3(C / 32, C / 32), 256, 0, stream>>>(projw, prT, C, C);
  transpose_cast<<<dim3(HF / 32, C / 32), 256, 0, stream>>>(fc1w, f1T, C, HF);
  transpose_cast<<<dim3(C / 32, HF / 32), 256, 0, stream>>>(fc2w, f2T, HF, C);

  layernorm_cast<<<M, 256, 0, stream>>>(x, ln1g, ln1b, hb);

  gemm_bt<<<dim3(3 * C / 128, M / 128), 256, 0, stream>>>(
      hb, wqkvT, M, 3 * C, C, nullptr, nullptr, nullptr, qkvb, 0);

  attention_kernel<<<128, 256, 0, stream>>>(qkvb, ob);

  const dim3 g1(C / 128, M / 128);
  gemm_bt<<<g1, 256, 0, stream>>>(ob, prT, M, C, C, projb, x, out, nullptr, 1);

  layernorm_cast<<<M, 256, 0, stream>>>(out, ln2g, ln2b, h2);

  gemm_bt<<<dim3(HF / 128, M / 128), 256, 0, stream>>>(h2, f1T, M, HF, C, fc1b, nullptr, nullptr, h3, 2);
  gemm_bt<<<g1, 256, 0, stream>>>(h3, f2T, M, C, HF, fc2b, out, out, nullptr, 1);
}

// Round 4
// 1361.275 us; speedup vs baseline: 1.1656x; 1.1066x over previous
//
#include <hip/hip_runtime.h>
#include <cmath>

typedef __attribute__((ext_vector_type(8))) _Float16 f16x8;
typedef __attribute__((ext_vector_type(8))) unsigned short u16x8;
typedef __attribute__((ext_vector_type(4))) float f32x4;

__device__ __forceinline__ unsigned short f2h(float f) {
  return __builtin_bit_cast(unsigned short, (_Float16)f);
}

__device__ __forceinline__ void async16(const void* gp, void* lp) {
  __builtin_amdgcn_global_load_lds(
      (const __attribute__((address_space(1))) void*)gp,
      (__attribute__((address_space(3))) void*)lp, 16, 0, 0);
}

// ---------------- weight transpose + cast: W (K x N) f32 -> WT (N x K) f16 ----
__global__ __launch_bounds__(256) void transpose_cast(
    const float* __restrict__ W, unsigned short* __restrict__ WT, int K, int N) {
  __shared__ float tile[32][33];
  const int tx = threadIdx.x & 31, ty = threadIdx.x >> 5;
  const int n0 = blockIdx.x * 32, k0 = blockIdx.y * 32;
#pragma unroll
  for (int r = 0; r < 4; ++r)
    tile[ty + 8 * r][tx] = W[(size_t)(k0 + ty + 8 * r) * N + n0 + tx];
  __syncthreads();
#pragma unroll
  for (int r = 0; r < 4; ++r)
    WT[(size_t)(n0 + ty + 8 * r) * K + k0 + tx] = f2h(tile[tx][ty + 8 * r]);
}

// ---------------- layernorm (C=1024) f32 -> f16 ------------------------------
__global__ __launch_bounds__(256) void layernorm_cast(
    const float* __restrict__ x, const float* __restrict__ g,
    const float* __restrict__ bt, unsigned short* __restrict__ out) {
  const int row = blockIdx.x, tid = threadIdx.x;
  const float4 v = ((const float4*)(x + (size_t)row * 1024))[tid];
  float s = v.x + v.y + v.z + v.w;
  float ss = v.x * v.x + v.y * v.y + v.z * v.z + v.w * v.w;
#pragma unroll
  for (int off = 32; off >= 1; off >>= 1) {
    s += __shfl_down(s, off);
    ss += __shfl_down(ss, off);
  }
  __shared__ float red[10];
  const int wave = tid >> 6, lane = tid & 63;
  if (lane == 0) { red[wave] = s; red[4 + wave] = ss; }
  __syncthreads();
  if (tid == 0) {
    float S = red[0] + red[1] + red[2] + red[3];
    float SS = red[4] + red[5] + red[6] + red[7];
    float mu = S * (1.f / 1024.f);
    float var = SS * (1.f / 1024.f) - mu * mu;
    red[8] = mu;
    red[9] = rsqrtf(var + 1e-5f);
  }
  __syncthreads();
  const float mu = red[8], rs = red[9];
  const float4 gv = ((const float4*)g)[tid];
  const float4 bv = ((const float4*)bt)[tid];
  ushort4 r;
  r.x = f2h((v.x - mu) * rs * gv.x + bv.x);
  r.y = f2h((v.y - mu) * rs * gv.y + bv.y);
  r.z = f2h((v.z - mu) * rs * gv.z + bv.z);
  r.w = f2h((v.w - mu) * rs * gv.w + bv.w);
  ((ushort4*)(out + (size_t)row * 1024))[tid] = r;
}

// ---------------- f16 GEMM, BK=64: C = A (MxK) * BT^T (BT is NxK) ------------
// LDS layout [kh][128][32] with the verified zero-conflict XOR swizzle per
// 32-wide sub-tile; two k-sub-stages per barrier pair (halved barrier drains).
// mode 0: outB = f16(acc)
// mode 1: outF = acc + bias[col] + resid[row][col]   (fp32 out)
// mode 2: outB = f16(gelu_exact(acc + bias[col]))
__global__ __launch_bounds__(256) void gemm_bt(
    const unsigned short* __restrict__ A, const unsigned short* __restrict__ BT,
    int M, int N, int K,
    const float* __restrict__ bias, const float* __restrict__ resid,
    float* __restrict__ outF, unsigned short* __restrict__ outB, int mode) {
  __shared__ unsigned short sA[2 * 128 * 32];
  __shared__ unsigned short sB[2 * 128 * 32];
  const int tid = threadIdx.x, wave = tid >> 6, lane = tid & 63;
  const int l16 = lane & 15, g16 = lane >> 4;
  const int wm = wave & 1, wn = wave >> 1;

  // XCD-aware remap: linear ids differing only in (lin&7) share the same
  // B col-tile and are temporally adjacent on the same XCD.
  const int lin = blockIdx.y * gridDim.x + blockIdx.x;
  const int t_ = lin >> 3;
  const int bx = t_ % gridDim.x;
  const int by = (lin & 7) + 8 * (t_ / gridDim.x);
  const int row0 = by * 128, col0 = bx * 128;

  const int r_ = tid >> 2;
  const int s_ = ((tid & 3) ^ ((tid >> 3) & 3)) * 8;  // XOR segment swizzle
  const unsigned short* pA = A + (size_t)(row0 + r_) * K + s_;
  const unsigned short* pB = BT + (size_t)(col0 + r_) * K + s_;
  unsigned short* dA = sA + wave * 512;
  unsigned short* dB = sB + wave * 512;
  const size_t rstep = (size_t)64 * K;

  f32x4 acc[4][4] = {};

  for (int k0 = 0; k0 < K; k0 += 64) {
    __syncthreads();
    async16(pA, dA);
    async16(pA + rstep, dA + 2048);
    async16(pA + 32, dA + 4096);
    async16(pA + rstep + 32, dA + 6144);
    async16(pB, dB);
    async16(pB + rstep, dB + 2048);
    async16(pB + 32, dB + 4096);
    async16(pB + rstep + 32, dB + 6144);
    pA += 64;
    pB += 64;
    __syncthreads();
#pragma unroll
    for (int kk = 0; kk < 2; ++kk) {
      f16x8 af[4], bf[4];
#pragma unroll
      for (int i = 0; i < 4; ++i) {
        const int ra = wm * 64 + i * 16 + l16;
        af[i] = __builtin_bit_cast(f16x8,
            *(const u16x8*)&sA[kk * 4096 + ra * 32 + (g16 ^ ((ra >> 1) & 3)) * 8]);
      }
#pragma unroll
      for (int j = 0; j < 4; ++j) {
        const int rb = wn * 64 + j * 16 + l16;
        bf[j] = __builtin_bit_cast(f16x8,
            *(const u16x8*)&sB[kk * 4096 + rb * 32 + (g16 ^ ((rb >> 1) & 3)) * 8]);
      }
#pragma unroll
      for (int i = 0; i < 4; ++i)
#pragma unroll
        for (int j = 0; j < 4; ++j)
          acc[i][j] = __builtin_amdgcn_mfma_f32_16x16x32_f16(af[i], bf[j], acc[i][j], 0, 0, 0);
    }
  }

#pragma unroll
  for (int i = 0; i < 4; ++i) {
#pragma unroll
    for (int j = 0; j < 4; ++j) {
      const int col = col0 + wn * 64 + j * 16 + l16;
      const float bcol = (mode != 0) ? bias[col] : 0.f;
#pragma unroll
      for (int r = 0; r < 4; ++r) {
        const int row = row0 + wm * 64 + i * 16 + g16 * 4 + r;
        const size_t idx = (size_t)row * N + col;
        const float val = acc[i][j][r];
        if (mode == 1) {
          outF[idx] = val + bcol + resid[idx];
        } else if (mode == 2) {
          const float t = val + bcol;
          outB[idx] = f2h(0.5f * t * (1.0f + erff(t * 0.70710678118f)));
        } else {
          outB[idx] = f2h(val);
        }
      }
    }
  }
}

// ---------------- attention stage 1: partial S = Q^T K over an n-chunk -------
// qkv: (M x 3072) f16. block = (bh*4 + chunk); writes sp[block][64][64] fp32.
__global__ __launch_bounds__(256) void attn_qk_part(
    const unsigned short* __restrict__ qkv, float* __restrict__ sp) {
  constexpr int ST = 72;
  __shared__ unsigned short sQT[64 * ST];  // [dd][n]
  __shared__ unsigned short sKT[64 * ST];  // [e][n]
  const int bx = blockIdx.x, bh = bx >> 2, chunk = bx & 3;
  const int b = bh >> 4, h = bh & 15;
  const size_t base = (size_t)b * 4096 * 3072 + (size_t)h * 64;
  const int tid = threadIdx.x, wave = tid >> 6, lane = tid & 63;
  const int l16 = lane & 15, g16 = lane >> 4;
  const int wm = wave & 1, wn = wave >> 1;
  const int srow = tid >> 2, sseg = tid & 3;

  f32x4 acc[2][2] = {};

  for (int ntl = 0; ntl < 16; ++ntl) {
    const int nt = chunk * 16 + ntl;
    __syncthreads();
    const size_t roff = base + (size_t)(nt * 64 + srow) * 3072 + sseg * 16;
    const u16x8 q0 = *(const u16x8*)(qkv + roff);
    const u16x8 q1 = *(const u16x8*)(qkv + roff + 8);
    const u16x8 k0 = *(const u16x8*)(qkv + roff + 1024);
    const u16x8 k1 = *(const u16x8*)(qkv + roff + 1032);
#pragma unroll
    for (int ii = 0; ii < 8; ++ii) {
      sQT[(sseg * 16 + ii) * ST + srow] = q0[ii];
      sQT[(sseg * 16 + 8 + ii) * ST + srow] = q1[ii];
      sKT[(sseg * 16 + ii) * ST + srow] = k0[ii];
      sKT[(sseg * 16 + 8 + ii) * ST + srow] = k1[ii];
    }
    __syncthreads();
#pragma unroll
    for (int kk = 0; kk < 2; ++kk) {
      f16x8 aq[2], bk[2];
#pragma unroll
      for (int i = 0; i < 2; ++i)
        aq[i] = __builtin_bit_cast(f16x8,
            *(const u16x8*)&sQT[(wm * 32 + i * 16 + l16) * ST + kk * 32 + g16 * 8]);
#pragma unroll
      for (int j = 0; j < 2; ++j)
        bk[j] = __builtin_bit_cast(f16x8,
            *(const u16x8*)&sKT[(wn * 32 + j * 16 + l16) * ST + kk * 32 + g16 * 8]);
#pragma unroll
      for (int i = 0; i < 2; ++i)
#pragma unroll
        for (int j = 0; j < 2; ++j)
          acc[i][j] = __builtin_amdgcn_mfma_f32_16x16x32_f16(aq[i], bk[j], acc[i][j], 0, 0, 0);
    }
  }

  float* o = sp + (size_t)bx * 4096;
#pragma unroll
  for (int i = 0; i < 2; ++i)
#pragma unroll
    for (int j = 0; j < 2; ++j)
#pragma unroll
      for (int r = 0; r < 4; ++r)
        o[(wm * 32 + i * 16 + g16 * 4 + r) * 64 + (wn * 32 + j * 16 + l16)] = acc[i][j][r];
}

// ---------------- attention stage 2: chunk-reduce + softmax -> Am (f16) ------
__global__ __launch_bounds__(64) void attn_softmax(
    const float* __restrict__ sp, unsigned short* __restrict__ am) {
  const int bh = blockIdx.x, dd = threadIdx.x;
  const float* p = sp + (size_t)bh * 4 * 4096 + dd * 64;
  float row[64];
#pragma unroll
  for (int e4 = 0; e4 < 16; ++e4) {
    const float4 a = ((const float4*)p)[e4];
    const float4 b_ = ((const float4*)(p + 4096))[e4];
    const float4 c_ = ((const float4*)(p + 8192))[e4];
    const float4 d_ = ((const float4*)(p + 12288))[e4];
    row[4 * e4 + 0] = a.x + b_.x + c_.x + d_.x;
    row[4 * e4 + 1] = a.y + b_.y + c_.y + d_.y;
    row[4 * e4 + 2] = a.z + b_.z + c_.z + d_.z;
    row[4 * e4 + 3] = a.w + b_.w + c_.w + d_.w;
  }
  float mx = -1e30f;
#pragma unroll
  for (int e = 0; e < 64; ++e) mx = fmaxf(mx, row[e]);
  float sum = 0.f;
#pragma unroll
  for (int e = 0; e < 64; ++e) {
    row[e] = __expf(0.125f * (row[e] - mx));
    sum += row[e];
  }
  const float inv = 1.0f / sum;
  unsigned short* q = am + (size_t)bh * 4096 + dd * 64;
#pragma unroll
  for (int e = 0; e < 64; ++e) q[e] = f2h(row[e] * inv);
}

// ---------------- attention stage 3: O = A * V over an n-chunk ---------------
// scrambled output: o[b*4096 + dd*64 + h*4 + (n>>10)][n & 1023]
__global__ __launch_bounds__(256) void attn_pv(
    const unsigned short* __restrict__ qkv, const unsigned short* __restrict__ am,
    unsigned short* __restrict__ o) {
  const int bx = blockIdx.x, bh = bx >> 2, chunk = bx & 3;
  const int b = bh >> 4, h = bh & 15;
  const size_t base = (size_t)b * 4096 * 3072 + (size_t)h * 64;
  const int tid = threadIdx.x, wave = tid >> 6, lane = tid & 63;
  const int l16 = lane & 15, g16 = lane >> 4;
  const int wm = wave & 1, wn = wave >> 1;

  f16x8 amf[2][2];
#pragma unroll
  for (int i = 0; i < 2; ++i)
#pragma unroll
    for (int kk = 0; kk < 2; ++kk)
      amf[i][kk] = __builtin_bit_cast(f16x8,
          *(const u16x8*)(am + (size_t)bh * 4096 +
                          (wm * 32 + i * 16 + l16) * 64 + kk * 32 + g16 * 8));

  for (int ntl = 0; ntl < 16; ++ntl) {
    const int nt = chunk * 16 + ntl;
    f32x4 oc[2][2] = {};
#pragma unroll
    for (int kk = 0; kk < 2; ++kk) {
#pragma unroll
      for (int j = 0; j < 2; ++j) {
        const f16x8 vf = __builtin_bit_cast(f16x8,
            *(const u16x8*)(qkv + base + 2048 +
                            (size_t)(nt * 64 + wn * 32 + j * 16 + l16) * 3072 +
                            kk * 32 + g16 * 8));
#pragma unroll
        for (int i = 0; i < 2; ++i)
          oc[i][j] = __builtin_amdgcn_mfma_f32_16x16x32_f16(amf[i][kk], vf, oc[i][j], 0, 0, 0);
      }
    }
#pragma unroll
    for (int i = 0; i < 2; ++i)
#pragma unroll
      for (int j = 0; j < 2; ++j)
#pragma unroll
        for (int r = 0; r < 4; ++r) {
          const int dd = wm * 32 + i * 16 + g16 * 4 + r;
          const int nf = nt * 64 + wn * 32 + j * 16 + l16;
          const int row = b * 4096 + dd * 64 + h * 4 + (nf >> 10);
          o[(size_t)row * 1024 + (nf & 1023)] = f2h(oc[i][j][r]);
        }
  }
}

// -----------------------------------------------------------------------------
extern "C" void kernel_launch(void* const* d_in, const int* in_sizes, int n_in,
                              void* d_out, int out_size, void* d_ws, size_t ws_size,
                              hipStream_t stream) {
  (void)in_sizes; (void)n_in; (void)out_size; (void)ws_size;
  const float* x = (const float*)d_in[0];
  const float* ln1g = (const float*)d_in[1];
  const float* ln1b = (const float*)d_in[2];
  const float* ln2g = (const float*)d_in[3];
  const float* ln2b = (const float*)d_in[4];
  const float* wq = (const float*)d_in[5];
  const float* wk = (const float*)d_in[6];
  const float* wv = (const float*)d_in[7];
  const float* projw = (const float*)d_in[8];
  const float* projb = (const float*)d_in[9];
  const float* fc1w = (const float*)d_in[10];
  const float* fc1b = (const float*)d_in[11];
  const float* fc2w = (const float*)d_in[12];
  const float* fc2b = (const float*)d_in[13];
  float* out = (float*)d_out;

  const int M = 8 * 4096, C = 1024, HF = 2048;

  unsigned short* p = (unsigned short*)d_ws;
  unsigned short* wqkvT = p; p += (size_t)3 * C * C;  // [3072 x 1024]
  unsigned short* prT = p; p += (size_t)C * C;
  unsigned short* f1T = p; p += (size_t)HF * C;
  unsigned short* f2T = p; p += (size_t)C * HF;
  unsigned short* hb = p;  p += (size_t)M * C;
  unsigned short* qkvb = p; p += (size_t)M * 3 * C;
  unsigned short* ob = hb;           // reuse: hb dead after qkv GEMM
  unsigned short* h2 = qkvb;         // reuse: qkv dead after attention (M x C)
  unsigned short* h3 = qkvb + (size_t)M * C;  // (M x HF)
  // attention scratch aliases (regions dead during attention):
  float* Spart = (float*)hb;         // 512 * 64 * 64 fp32 = 8 MB (hb dead, ob not yet written)
  unsigned short* Am = wqkvT;        // 128 * 4096 f16 = 1 MB (wqkvT dead after qkv GEMM)

  transpose_cast<<<dim3(C / 32, C / 32), 256, 0, stream>>>(wq, wqkvT, C, C);
  transpose_cast<<<dim3(C / 32, C / 32), 256, 0, stream>>>(wk, wqkvT + (size_t)C * C, C, C);
  transpose_cast<<<dim3(C / 32, C / 32), 256, 0, stream>>>(wv, wqkvT + (size_t)2 * C * C, C, C);
  transpose_cast<<<dim3(C / 32, C / 32), 256, 0, stream>>>(projw, prT, C, C);
  transpose_cast<<<dim3(HF / 32, C / 32), 256, 0, stream>>>(fc1w, f1T, C, HF);
  transpose_cast<<<dim3(C / 32, HF / 32), 256, 0, stream>>>(fc2w, f2T, HF, C);

  layernorm_cast<<<M, 256, 0, stream>>>(x, ln1g, ln1b, hb);

  gemm_bt<<<dim3(3 * C / 128, M / 128), 256, 0, stream>>>(
      hb, wqkvT, M, 3 * C, C, nullptr, nullptr, nullptr, qkvb, 0);

  attn_qk_part<<<512, 256, 0, stream>>>(qkvb, Spart);
  attn_softmax<<<128, 64, 0, stream>>>(Spart, Am);
  attn_pv<<<512, 256, 0, stream>>>(qkvb, Am, ob);

  const dim3 g1(C / 128, M / 128);
  gemm_bt<<<g1, 256, 0, stream>>>(ob, prT, M, C, C, projb, x, out, nullptr, 1);

  layernorm_cast<<<M, 256, 0, stream>>>(out, ln2g, ln2b, h2);

  gemm_bt<<<dim3(HF / 128, M / 128), 256, 0, stream>>>(h2, f1T, M, HF, C, fc1b, nullptr, nullptr, h3, 2);
  gemm_bt<<<g1, 256, 0, stream>>>(h3, f2T, M, C, HF, fc2b, out, out, nullptr, 1);
}

// Round 5
// 1139.629 us; speedup vs baseline: 1.3922x; 1.1945x over previous
//
#include <hip/hip_runtime.h>
#include <cmath>

typedef __attribute__((ext_vector_type(8))) _Float16 f16x8;
typedef __attribute__((ext_vector_type(8))) unsigned short u16x8;
typedef __attribute__((ext_vector_type(4))) float f32x4;

__device__ __forceinline__ unsigned short f2h(float f) {
  return __builtin_bit_cast(unsigned short, (_Float16)f);
}
__device__ __forceinline__ float h2f(unsigned short u) {
  return (float)__builtin_bit_cast(_Float16, u);
}

__device__ __forceinline__ void async16(const void* gp, void* lp) {
  __builtin_amdgcn_global_load_lds(
      (const __attribute__((address_space(1))) void*)gp,
      (__attribute__((address_space(3))) void*)lp, 16, 0, 0);
}

// ---------------- weight transpose + cast: W (K x N) f32 -> WT (N x K) f16 ----
__global__ __launch_bounds__(256) void transpose_cast(
    const float* __restrict__ W, unsigned short* __restrict__ WT, int K, int N) {
  __shared__ float tile[32][33];
  const int tx = threadIdx.x & 31, ty = threadIdx.x >> 5;
  const int n0 = blockIdx.x * 32, k0 = blockIdx.y * 32;
#pragma unroll
  for (int r = 0; r < 4; ++r)
    tile[ty + 8 * r][tx] = W[(size_t)(k0 + ty + 8 * r) * N + n0 + tx];
  __syncthreads();
#pragma unroll
  for (int r = 0; r < 4; ++r)
    WT[(size_t)(n0 + ty + 8 * r) * K + k0 + tx] = f2h(tile[tx][ty + 8 * r]);
}

// ---------------- layernorm (C=1024) f32 -> f16 ------------------------------
__global__ __launch_bounds__(256) void layernorm_cast(
    const float* __restrict__ x, const float* __restrict__ g,
    const float* __restrict__ bt, unsigned short* __restrict__ out) {
  const int row = blockIdx.x, tid = threadIdx.x;
  const float4 v = ((const float4*)(x + (size_t)row * 1024))[tid];
  float s = v.x + v.y + v.z + v.w;
  float ss = v.x * v.x + v.y * v.y + v.z * v.z + v.w * v.w;
#pragma unroll
  for (int off = 32; off >= 1; off >>= 1) {
    s += __shfl_down(s, off);
    ss += __shfl_down(ss, off);
  }
  __shared__ float red[10];
  const int wave = tid >> 6, lane = tid & 63;
  if (lane == 0) { red[wave] = s; red[4 + wave] = ss; }
  __syncthreads();
  if (tid == 0) {
    float S = red[0] + red[1] + red[2] + red[3];
    float SS = red[4] + red[5] + red[6] + red[7];
    float mu = S * (1.f / 1024.f);
    float var = SS * (1.f / 1024.f) - mu * mu;
    red[8] = mu;
    red[9] = rsqrtf(var + 1e-5f);
  }
  __syncthreads();
  const float mu = red[8], rs = red[9];
  const float4 gv = ((const float4*)g)[tid];
  const float4 bv = ((const float4*)bt)[tid];
  ushort4 r;
  r.x = f2h((v.x - mu) * rs * gv.x + bv.x);
  r.y = f2h((v.y - mu) * rs * gv.y + bv.y);
  r.z = f2h((v.z - mu) * rs * gv.z + bv.z);
  r.w = f2h((v.w - mu) * rs * gv.w + bv.w);
  ((ushort4*)(out + (size_t)row * 1024))[tid] = r;
}

// ---------------- fused residual + layernorm --------------------------------
// out = x + pr + pb  (fp32), h2 = LN(out)*g + b  (f16)
__global__ __launch_bounds__(256) void resid_ln(
    const float* __restrict__ x, const unsigned short* __restrict__ pr,
    const float* __restrict__ pb, const float* __restrict__ g,
    const float* __restrict__ bt, float* __restrict__ out,
    unsigned short* __restrict__ h2) {
  const int row = blockIdx.x, tid = threadIdx.x;
  const size_t off = (size_t)row * 1024;
  const float4 xv = ((const float4*)(x + off))[tid];
  const ushort4 pv = ((const ushort4*)(pr + off))[tid];
  const float4 bb = ((const float4*)pb)[tid];
  float4 v;
  v.x = xv.x + h2f(pv.x) + bb.x;
  v.y = xv.y + h2f(pv.y) + bb.y;
  v.z = xv.z + h2f(pv.z) + bb.z;
  v.w = xv.w + h2f(pv.w) + bb.w;
  ((float4*)(out + off))[tid] = v;
  float s = v.x + v.y + v.z + v.w;
  float ss = v.x * v.x + v.y * v.y + v.z * v.z + v.w * v.w;
#pragma unroll
  for (int o = 32; o >= 1; o >>= 1) {
    s += __shfl_down(s, o);
    ss += __shfl_down(ss, o);
  }
  __shared__ float red[10];
  const int wave = tid >> 6, lane = tid & 63;
  if (lane == 0) { red[wave] = s; red[4 + wave] = ss; }
  __syncthreads();
  if (tid == 0) {
    float S = red[0] + red[1] + red[2] + red[3];
    float SS = red[4] + red[5] + red[6] + red[7];
    float mu = S * (1.f / 1024.f);
    float var = SS * (1.f / 1024.f) - mu * mu;
    red[8] = mu;
    red[9] = rsqrtf(var + 1e-5f);
  }
  __syncthreads();
  const float mu = red[8], rs = red[9];
  const float4 gv = ((const float4*)g)[tid];
  const float4 bv = ((const float4*)bt)[tid];
  ushort4 r;
  r.x = f2h((v.x - mu) * rs * gv.x + bv.x);
  r.y = f2h((v.y - mu) * rs * gv.y + bv.y);
  r.z = f2h((v.z - mu) * rs * gv.z + bv.z);
  r.w = f2h((v.w - mu) * rs * gv.w + bv.w);
  ((ushort4*)(h2 + off))[tid] = r;
}

// ---------------- final residual add: out += y + b ---------------------------
__global__ __launch_bounds__(256) void resid_add(
    float* __restrict__ out, const unsigned short* __restrict__ y,
    const float* __restrict__ b) {
  const int row = blockIdx.x, tid = threadIdx.x;
  const size_t off = (size_t)row * 1024;
  float4 o = ((const float4*)(out + off))[tid];
  const ushort4 yv = ((const ushort4*)(y + off))[tid];
  const float4 bv = ((const float4*)b)[tid];
  o.x += h2f(yv.x) + bv.x;
  o.y += h2f(yv.y) + bv.y;
  o.z += h2f(yv.z) + bv.z;
  o.w += h2f(yv.w) + bv.w;
  ((float4*)(out + off))[tid] = o;
}

// ---------------- f16 GEMM, BK=64: C = A (MxK) * BT^T (BT is NxK) ------------
// Zero-conflict XOR-swizzled LDS; XCD-aware block remap; f16 output with
// per-wave LDS-staged vectorized (dwordx4) stores. gelu!=0: out = gelu(acc+bias).
__global__ __launch_bounds__(256) void gemm_bt(
    const unsigned short* __restrict__ A, const unsigned short* __restrict__ BT,
    int M, int N, int K,
    const float* __restrict__ bias, unsigned short* __restrict__ outB, int gelu) {
  __shared__ unsigned short smem[17408];  // 16384 K-loop + epilogue reuse
  unsigned short* sA = smem;
  unsigned short* sB = smem + 8192;
  const int tid = threadIdx.x, wave = tid >> 6, lane = tid & 63;
  const int l16 = lane & 15, g16 = lane >> 4;
  const int wm = wave & 1, wn = wave >> 1;

  // XCD-aware remap: same A row-tile stays on one XCD, temporally adjacent.
  const int lin = blockIdx.y * gridDim.x + blockIdx.x;
  const int t_ = lin >> 3;
  const int bx = t_ % gridDim.x;
  const int by = (lin & 7) + 8 * (t_ / gridDim.x);
  const int row0 = by * 128, col0 = bx * 128;

  const int r_ = tid >> 2;
  const int s_ = ((tid & 3) ^ ((tid >> 3) & 3)) * 8;  // XOR segment swizzle
  const unsigned short* pA = A + (size_t)(row0 + r_) * K + s_;
  const unsigned short* pB = BT + (size_t)(col0 + r_) * K + s_;
  unsigned short* dA = sA + wave * 512;
  unsigned short* dB = sB + wave * 512;
  const size_t rstep = (size_t)64 * K;

  f32x4 acc[4][4] = {};

  for (int k0 = 0; k0 < K; k0 += 64) {
    __syncthreads();
    async16(pA, dA);
    async16(pA + rstep, dA + 2048);
    async16(pA + 32, dA + 4096);
    async16(pA + rstep + 32, dA + 6144);
    async16(pB, dB);
    async16(pB + rstep, dB + 2048);
    async16(pB + 32, dB + 4096);
    async16(pB + rstep + 32, dB + 6144);
    pA += 64;
    pB += 64;
    __syncthreads();
#pragma unroll
    for (int kk = 0; kk < 2; ++kk) {
      f16x8 af[4], bf[4];
#pragma unroll
      for (int i = 0; i < 4; ++i) {
        const int ra = wm * 64 + i * 16 + l16;
        af[i] = __builtin_bit_cast(f16x8,
            *(const u16x8*)&sA[kk * 4096 + ra * 32 + (g16 ^ ((ra >> 1) & 3)) * 8]);
      }
#pragma unroll
      for (int j = 0; j < 4; ++j) {
        const int rb = wn * 64 + j * 16 + l16;
        bf[j] = __builtin_bit_cast(f16x8,
            *(const u16x8*)&sB[kk * 4096 + rb * 32 + (g16 ^ ((rb >> 1) & 3)) * 8]);
      }
#pragma unroll
      for (int i = 0; i < 4; ++i)
#pragma unroll
        for (int j = 0; j < 4; ++j)
          acc[i][j] = __builtin_amdgcn_mfma_f32_16x16x32_f16(af[i], bf[j], acc[i][j], 0, 0, 0);
    }
  }

  // ---- epilogue: acc -> f16 via wave-private LDS (stride 68), 16B stores ----
  __syncthreads();  // all waves done reading sA/sB
  unsigned short* scr = smem + wave * 4352;  // 64 x 68 f16 per wave
#pragma unroll
  for (int j = 0; j < 4; ++j) {
    const float bcol = gelu ? bias[col0 + wn * 64 + j * 16 + l16] : 0.f;
#pragma unroll
    for (int i = 0; i < 4; ++i)
#pragma unroll
      for (int r = 0; r < 4; ++r) {
        float val = acc[i][j][r] + bcol;
        if (gelu) val = 0.5f * val * (1.0f + erff(val * 0.70710678118f));
        scr[(i * 16 + g16 * 4 + r) * 68 + j * 16 + l16] = f2h(val);
      }
  }
#pragma unroll
  for (int rr = 0; rr < 8; ++rr) {
    const int lr = rr * 8 + (lane >> 3);
    const int lc = (lane & 7) * 8;
    const u16x8 val = *(const u16x8*)&scr[lr * 68 + lc];
    *(u16x8*)(outB + (size_t)(row0 + wm * 64 + lr) * N + col0 + wn * 64 + lc) = val;
  }
}

// ---------------- attention stage 1: partial S = Q^T K over an n-chunk -------
__global__ __launch_bounds__(256) void attn_qk_part(
    const unsigned short* __restrict__ qkv, float* __restrict__ sp) {
  constexpr int ST = 72;
  __shared__ unsigned short sQT[64 * ST];  // [dd][n]
  __shared__ unsigned short sKT[64 * ST];  // [e][n]
  const int bx = blockIdx.x, bh = bx >> 2, chunk = bx & 3;
  const int b = bh >> 4, h = bh & 15;
  const size_t base = (size_t)b * 4096 * 3072 + (size_t)h * 64;
  const int tid = threadIdx.x, wave = tid >> 6, lane = tid & 63;
  const int l16 = lane & 15, g16 = lane >> 4;
  const int wm = wave & 1, wn = wave >> 1;
  const int srow = tid >> 2, sseg = tid & 3;

  f32x4 acc[2][2] = {};

  for (int ntl = 0; ntl < 16; ++ntl) {
    const int nt = chunk * 16 + ntl;
    __syncthreads();
    const size_t roff = base + (size_t)(nt * 64 + srow) * 3072 + sseg * 16;
    const u16x8 q0 = *(const u16x8*)(qkv + roff);
    const u16x8 q1 = *(const u16x8*)(qkv + roff + 8);
    const u16x8 k0 = *(const u16x8*)(qkv + roff + 1024);
    const u16x8 k1 = *(const u16x8*)(qkv + roff + 1032);
#pragma unroll
    for (int ii = 0; ii < 8; ++ii) {
      sQT[(sseg * 16 + ii) * ST + srow] = q0[ii];
      sQT[(sseg * 16 + 8 + ii) * ST + srow] = q1[ii];
      sKT[(sseg * 16 + ii) * ST + srow] = k0[ii];
      sKT[(sseg * 16 + 8 + ii) * ST + srow] = k1[ii];
    }
    __syncthreads();
#pragma unroll
    for (int kk = 0; kk < 2; ++kk) {
      f16x8 aq[2], bk[2];
#pragma unroll
      for (int i = 0; i < 2; ++i)
        aq[i] = __builtin_bit_cast(f16x8,
            *(const u16x8*)&sQT[(wm * 32 + i * 16 + l16) * ST + kk * 32 + g16 * 8]);
#pragma unroll
      for (int j = 0; j < 2; ++j)
        bk[j] = __builtin_bit_cast(f16x8,
            *(const u16x8*)&sKT[(wn * 32 + j * 16 + l16) * ST + kk * 32 + g16 * 8]);
#pragma unroll
      for (int i = 0; i < 2; ++i)
#pragma unroll
        for (int j = 0; j < 2; ++j)
          acc[i][j] = __builtin_amdgcn_mfma_f32_16x16x32_f16(aq[i], bk[j], acc[i][j], 0, 0, 0);
    }
  }

  float* o = sp + (size_t)bx * 4096;
#pragma unroll
  for (int i = 0; i < 2; ++i)
#pragma unroll
    for (int j = 0; j < 2; ++j)
#pragma unroll
      for (int r = 0; r < 4; ++r)
        o[(wm * 32 + i * 16 + g16 * 4 + r) * 64 + (wn * 32 + j * 16 + l16)] = acc[i][j][r];
}

// ---------------- attention stage 2: chunk-reduce + softmax -> Am (f16) ------
__global__ __launch_bounds__(64) void attn_softmax(
    const float* __restrict__ sp, unsigned short* __restrict__ am) {
  const int bh = blockIdx.x, dd = threadIdx.x;
  const float* p = sp + (size_t)bh * 4 * 4096 + dd * 64;
  float row[64];
#pragma unroll
  for (int e4 = 0; e4 < 16; ++e4) {
    const float4 a = ((const float4*)p)[e4];
    const float4 b_ = ((const float4*)(p + 4096))[e4];
    const float4 c_ = ((const float4*)(p + 8192))[e4];
    const float4 d_ = ((const float4*)(p + 12288))[e4];
    row[4 * e4 + 0] = a.x + b_.x + c_.x + d_.x;
    row[4 * e4 + 1] = a.y + b_.y + c_.y + d_.y;
    row[4 * e4 + 2] = a.z + b_.z + c_.z + d_.z;
    row[4 * e4 + 3] = a.w + b_.w + c_.w + d_.w;
  }
  float mx = -1e30f;
#pragma unroll
  for (int e = 0; e < 64; ++e) mx = fmaxf(mx, row[e]);
  float sum = 0.f;
#pragma unroll
  for (int e = 0; e < 64; ++e) {
    row[e] = __expf(0.125f * (row[e] - mx));
    sum += row[e];
  }
  const float inv = 1.0f / sum;
  unsigned short* q = am + (size_t)bh * 4096 + dd * 64;
#pragma unroll
  for (int e = 0; e < 64; ++e) q[e] = f2h(row[e] * inv);
}

// ---------------- attention stage 3: O = A * V over an n-chunk ---------------
// scrambled output: o[b*4096 + dd*64 + h*4 + (n>>10)][n & 1023]
__global__ __launch_bounds__(256) void attn_pv(
    const unsigned short* __restrict__ qkv, const unsigned short* __restrict__ am,
    unsigned short* __restrict__ o) {
  const int bx = blockIdx.x, bh = bx >> 2, chunk = bx & 3;
  const int b = bh >> 4, h = bh & 15;
  const size_t base = (size_t)b * 4096 * 3072 + (size_t)h * 64;
  const int tid = threadIdx.x, wave = tid >> 6, lane = tid & 63;
  const int l16 = lane & 15, g16 = lane >> 4;
  const int wm = wave & 1, wn = wave >> 1;

  f16x8 amf[2][2];
#pragma unroll
  for (int i = 0; i < 2; ++i)
#pragma unroll
    for (int kk = 0; kk < 2; ++kk)
      amf[i][kk] = __builtin_bit_cast(f16x8,
          *(const u16x8*)(am + (size_t)bh * 4096 +
                          (wm * 32 + i * 16 + l16) * 64 + kk * 32 + g16 * 8));

  for (int ntl = 0; ntl < 16; ++ntl) {
    const int nt = chunk * 16 + ntl;
    f32x4 oc[2][2] = {};
#pragma unroll
    for (int kk = 0; kk < 2; ++kk) {
#pragma unroll
      for (int j = 0; j < 2; ++j) {
        const f16x8 vf = __builtin_bit_cast(f16x8,
            *(const u16x8*)(qkv + base + 2048 +
                            (size_t)(nt * 64 + wn * 32 + j * 16 + l16) * 3072 +
                            kk * 32 + g16 * 8));
#pragma unroll
        for (int i = 0; i < 2; ++i)
          oc[i][j] = __builtin_amdgcn_mfma_f32_16x16x32_f16(amf[i][kk], vf, oc[i][j], 0, 0, 0);
      }
    }
#pragma unroll
    for (int i = 0; i < 2; ++i)
#pragma unroll
      for (int j = 0; j < 2; ++j)
#pragma unroll
        for (int r = 0; r < 4; ++r) {
          const int dd = wm * 32 + i * 16 + g16 * 4 + r;
          const int nf = nt * 64 + wn * 32 + j * 16 + l16;
          const int row = b * 4096 + dd * 64 + h * 4 + (nf >> 10);
          o[(size_t)row * 1024 + (nf & 1023)] = f2h(oc[i][j][r]);
        }
  }
}

// -----------------------------------------------------------------------------
extern "C" void kernel_launch(void* const* d_in, const int* in_sizes, int n_in,
                              void* d_out, int out_size, void* d_ws, size_t ws_size,
                              hipStream_t stream) {
  (void)in_sizes; (void)n_in; (void)out_size; (void)ws_size;
  const float* x = (const float*)d_in[0];
  const float* ln1g = (const float*)d_in[1];
  const float* ln1b = (const float*)d_in[2];
  const float* ln2g = (const float*)d_in[3];
  const float* ln2b = (const float*)d_in[4];
  const float* wq = (const float*)d_in[5];
  const float* wk = (const float*)d_in[6];
  const float* wv = (const float*)d_in[7];
  const float* projw = (const float*)d_in[8];
  const float* projb = (const float*)d_in[9];
  const float* fc1w = (const float*)d_in[10];
  const float* fc1b = (const float*)d_in[11];
  const float* fc2w = (const float*)d_in[12];
  const float* fc2b = (const float*)d_in[13];
  float* out = (float*)d_out;

  const int M = 8 * 4096, C = 1024, HF = 2048;
  const size_t MC = (size_t)M * C;

  unsigned short* p = (unsigned short*)d_ws;
  unsigned short* wqkvT = p; p += (size_t)3 * C * C;  // [3072 x 1024]
  unsigned short* prT = p; p += (size_t)C * C;
  unsigned short* f1T = p; p += (size_t)HF * C;
  unsigned short* f2T = p; p += (size_t)C * HF;
  unsigned short* hb = p;  p += MC;          // region RA (64 MB)
  unsigned short* qkvb = p; p += 3 * MC;     // region RB (192 MB)
  // Aliases (lifetimes are strictly stream-ordered):
  float* Spart = (float*)hb;                 // attn scratch (8 MB), hb dead after qkv GEMM
  unsigned short* Am = wqkvT;                // 1 MB, wqkvT dead after qkv GEMM
  unsigned short* ob = hb;                   // attn output, clobbers consumed Spart
  unsigned short* projout = qkvb;            // RB[0,MC): qkvb dead after attn_pv
  unsigned short* h2 = qkvb + 2 * MC;        // RB[2MC,3MC)
  unsigned short* h3 = qkvb;                 // RB[0,2MC): projout dead after resid_ln
  unsigned short* yb = hb;                   // fc2 raw out, ob dead after proj GEMM

  transpose_cast<<<dim3(C / 32, C / 32), 256, 0, stream>>>(wq, wqkvT, C, C);
  transpose_cast<<<dim3(C / 32, C / 32), 256, 0, stream>>>(wk, wqkvT + (size_t)C * C, C, C);
  transpose_cast<<<dim3(C / 32, C / 32), 256, 0, stream>>>(wv, wqkvT + (size_t)2 * C * C, C, C);
  transpose_cast<<<dim3(C / 32, C / 32), 256, 0, stream>>>(projw, prT, C, C);
  transpose_cast<<<dim3(HF / 32, C / 32), 256, 0, stream>>>(fc1w, f1T, C, HF);
  transpose_cast<<<dim3(C / 32, HF / 32), 256, 0, stream>>>(fc2w, f2T, HF, C);

  layernorm_cast<<<M, 256, 0, stream>>>(x, ln1g, ln1b, hb);

  gemm_bt<<<dim3(3 * C / 128, M / 128), 256, 0, stream>>>(
      hb, wqkvT, M, 3 * C, C, nullptr, qkvb, 0);

  attn_qk_part<<<512, 256, 0, stream>>>(qkvb, Spart);
  attn_softmax<<<128, 64, 0, stream>>>(Spart, Am);
  attn_pv<<<512, 256, 0, stream>>>(qkvb, Am, ob);

  gemm_bt<<<dim3(C / 128, M / 128), 256, 0, stream>>>(
      ob, prT, M, C, C, nullptr, projout, 0);

  resid_ln<<<M, 256, 0, stream>>>(x, projout, projb, ln2g, ln2b, out, h2);

  gemm_bt<<<dim3(HF / 128, M / 128), 256, 0, stream>>>(
      h2, f1T, M, HF, C, fc1b, h3, 1);

  gemm_bt<<<dim3(C / 128, M / 128), 256, 0, stream>>>(
      h3, f2T, M, C, HF, nullptr, yb, 0);

  resid_add<<<M, 256, 0, stream>>>(out, yb, fc2b);
}